// Round 17
// baseline (128.447 us; speedup 1.0000x reference)
//
#include <hip/hip_runtime.h>

#define S_LEN 4096
#define BATCH 2
#define HID 512
#define HEADS 8
#define HD 64
#define NX (BATCH * S_LEN * HID)       // 4,194,304
#define WSZ (HID * HID)                // 262,144
#define NBH (BATCH * HEADS)            // 16
#define QB 64                          // q rows per attn block
#define NBLK (S_LEN / QB * NBH)        // 1024 blocks / flags

typedef short v8s __attribute__((ext_vector_type(8)));    // 8 bf16
typedef float v4f __attribute__((ext_vector_type(4)));    // 16x16 MFMA acc
typedef float v16f __attribute__((ext_vector_type(16)));  // 32x32 MFMA acc
typedef unsigned short ushort_t;
typedef const __attribute__((address_space(1))) unsigned gu32;
typedef __attribute__((address_space(3))) unsigned lu32;

__device__ __forceinline__ ushort_t f2bf(float f) {       // RNE
  unsigned u = __builtin_bit_cast(unsigned, f);
  u += 0x7fffu + ((u >> 16) & 1u);
  return (ushort_t)(u >> 16);
}
__device__ __forceinline__ unsigned pk2(float a, float b) {  // trunc pack
  return (__builtin_bit_cast(unsigned, a) >> 16) |
         (__builtin_bit_cast(unsigned, b) & 0xFFFF0000u);
}
__device__ __forceinline__ float fexp2(float x) {         // native v_exp_f32
  return __builtin_amdgcn_exp2f(x);
}

// fragment-linear Q/K: per head, per 32-row column (col = s>>5):
// off = col*2048 + ((d>>4)*64 + ((d>>3)&1)*32 + (s&31))*8 + (d&7)
// -> a 32x32x16 MFMA A/B frag (row/col = lane&31, k = 8*(lane>>5)+j) is one
//    v8s load at (kstep*64 + lane)*8: 1KB contiguous per wave instruction.

// ---------------------------------------------------------------------------
// Pre-convert fp32 -> bf16: x then Wq,Wk,Wv,Wo contiguous into dst.
// ---------------------------------------------------------------------------
__global__ __launch_bounds__(256) void cvt_k(
    const float* __restrict__ x,
    const float* __restrict__ wq, const float* __restrict__ wk,
    const float* __restrict__ wv, const float* __restrict__ wo,
    ushort_t* __restrict__ dst)
{
  const size_t e = ((size_t)blockIdx.x * 256 + threadIdx.x) * 4;
  const float* src; size_t off;
  if (e < NX) { src = x; off = e; }
  else {
    const size_t we = e - NX;
    const int wi = (int)(we >> 18);
    src = wi == 0 ? wq : wi == 1 ? wk : wi == 2 ? wv : wo;
    off = we & (WSZ - 1);
  }
  float4 v = *(const float4*)&src[off];
  uint2 u; u.x = pk2(v.x, v.y); u.y = pk2(v.z, v.w);
  *(uint2*)&dst[e] = u;
}

// ---------------------------------------------------------------------------
// QKV GEMM (bf16 in): 128x128 tile, BK=32, 4 waves (2x2), 16x16x32 MFMA,
// 4x4 frags/wave. Staging via global_load_lds width=16 (async, no VGPR
// round-trip; LINEAR [128][32] LDS dest required). 3 contiguous weights;
// Q,K written frag-linear (Q scaled 0.125*log2e), V plain [B,H,S,HD].
// ---------------------------------------------------------------------------
__global__ __launch_bounds__(256) void gemm_qkv(
    const ushort_t* __restrict__ X, const ushort_t* __restrict__ Wb,
    const float* __restrict__ bq, const float* __restrict__ bk, const float* __restrict__ bv,
    ushort_t* __restrict__ Qf, ushort_t* __restrict__ Kf, ushort_t* __restrict__ Vw,
    float qscale)
{
  __shared__ ushort_t As[128][32];    // linear (global_load_lds dest)
  __shared__ ushort_t Bs[128][32];
  const int t = threadIdx.x;
  const int lane = t & 63;
  const int l15 = lane & 15, lg = lane >> 4;
  const int w = t >> 6;
  const int wr = w >> 1, wc = w & 1;
  const int m0 = blockIdx.y * 128;
  const int wsel = blockIdx.x >> 2;
  const int e0 = (blockIdx.x & 3) * 128;
  const ushort_t* W = Wb + (size_t)wsel * WSZ;
  const float* bias = wsel == 0 ? bq : wsel == 1 ? bk : bv;
  const float osc = (wsel == 0) ? qscale : 1.0f;

  v4f acc[4][4] = {};
  const int r0 = t >> 2, c0 = (t & 3) * 8;

  for (int k0 = 0; k0 < HID; k0 += 32) {
    __syncthreads();   // previous tile fully consumed
    __builtin_amdgcn_global_load_lds(
        (gu32*)(const void*)&X[(size_t)(m0 + r0) * HID + k0 + c0],
        (lu32*)(void*)&As[r0][c0], 16, 0, 0);
    __builtin_amdgcn_global_load_lds(
        (gu32*)(const void*)&X[(size_t)(m0 + r0 + 64) * HID + k0 + c0],
        (lu32*)(void*)&As[r0 + 64][c0], 16, 0, 0);
    __builtin_amdgcn_global_load_lds(
        (gu32*)(const void*)&W[(size_t)(e0 + r0) * HID + k0 + c0],
        (lu32*)(void*)&Bs[r0][c0], 16, 0, 0);
    __builtin_amdgcn_global_load_lds(
        (gu32*)(const void*)&W[(size_t)(e0 + r0 + 64) * HID + k0 + c0],
        (lu32*)(void*)&Bs[r0 + 64][c0], 16, 0, 0);
    __syncthreads();   // drains vmcnt -> LDS tiles ready
    v8s a[4], b[4];
    #pragma unroll
    for (int fr = 0; fr < 4; ++fr)
      a[fr] = *(const v8s*)&As[wr * 64 + 16 * fr + l15][8 * lg];
    #pragma unroll
    for (int fc = 0; fc < 4; ++fc)
      b[fc] = *(const v8s*)&Bs[wc * 64 + 16 * fc + l15][8 * lg];
    #pragma unroll
    for (int fr = 0; fr < 4; ++fr)
      #pragma unroll
      for (int fc = 0; fc < 4; ++fc)
        acc[fr][fc] = __builtin_amdgcn_mfma_f32_16x16x32_bf16(a[fr], b[fc], acc[fr][fc], 0, 0, 0);
  }

  #pragma unroll
  for (int fr = 0; fr < 4; ++fr)
    #pragma unroll
    for (int fc = 0; fc < 4; ++fc) {
      const int e = e0 + wc * 64 + 16 * fc + l15;
      const float bval = bias[e];
      #pragma unroll
      for (int r = 0; r < 4; ++r) {
        // C/D layout: col = lane&15, row = 4*(lane>>4)+reg  [m89-verified]
        const int m = m0 + wr * 64 + 16 * fr + 4 * lg + r;
        const float v = (acc[fr][fc][r] + bval) * osc;
        const int bidx = m >> 12, s = m & (S_LEN - 1);
        const int hh = e >> 6, dh = e & 63;
        const size_t hb = ((size_t)(bidx * HEADS + hh)) * (size_t)(S_LEN * HD);
        if (wsel == 2) {
          Vw[hb + (size_t)s * HD + dh] = f2bf(v);
        } else {
          const size_t off = (size_t)(s >> 5) * 2048 +
              (size_t)(((dh >> 4) * 64 + ((dh >> 3) & 1) * 32 + (s & 31)) * 8 + (dh & 7));
          (wsel == 0 ? Qf : Kf)[hb + off] = f2bf(v);
        }
      }
    }
}

// ---------------------------------------------------------------------------
// Attention pass 1 (hot): JENSEN screen — NO exp2 in the loop. Per-row
// running MAX and SUM of log2-domain scores (R13's exact register envelope:
// qa[4]+M[16]+S[16]+two K buffers — proven 56 VGPR, spill-free). Flag iff
// M - S/4096 > 8.3. Conservative: exact-fire => M >= 12+S/4096-3.372 =
// S/4096+8.628 > S/4096+8.3 => Jensen-fire (Jensen: L >= 4096*2^mean).
// Spurious fires (~1 block, R7-observed) are resolved by attn_ref, not p2.
// 512 thr / 8 waves = rowset x key-quarter; 2-deep kA/kB4 ping-pong.
// Tripwire: WRITE_SIZE ~0.01 MB, VGPR ~56.
// ---------------------------------------------------------------------------
__global__ __launch_bounds__(512, 4) void attn_p1(
    const ushort_t* __restrict__ Qf, const ushort_t* __restrict__ Kf,
    int* __restrict__ JFlg)
{
  __shared__ float RedS[4][QB];   // [kq][row] partial score-sum
  __shared__ float RedM[4][QB];   // [kq][row] partial max
  __shared__ int bflag;
  const int t = threadIdx.x;
  const int lane = t & 63;
  const int l31 = lane & 31, hi = lane >> 5;
  const int w = t >> 6;           // 0..7
  const int rs = w >> 2;          // rowset (32 q rows each)
  const int kq = w & 3;           // key quarter
  const int lin = blockIdx.x;
  const int bh = ((lin & 7) << 1) | ((lin >> 3) & 1);   // 2 heads per XCD
  const int q0 = (lin >> 4) * QB;
  if (t == 0) bflag = 0;

  const size_t hoff = (size_t)bh * (size_t)(S_LEN * HD);
  const ushort_t* Qb = Qf + hoff + ((size_t)(q0 >> 5) + rs) * 2048;
  const ushort_t* Kb = Kf + hoff;

  v8s qa[4];
  #pragma unroll
  for (int ks = 0; ks < 4; ++ks)
    qa[ks] = *(const v8s*)&Qb[(ks * 64 + lane) * 8];

  float M[16], S[16];
  #pragma unroll
  for (int j = 0; j < 16; ++j) { M[j] = -1e30f; S[j] = 0.f; }

  v8s kA[4], kB4[4];
  {
    const ushort_t* kc = Kb + (size_t)kq * 2048;
    #pragma unroll
    for (int ks = 0; ks < 4; ++ks)
      kA[ks] = *(const v8s*)&kc[(ks * 64 + lane) * 8];
  }

#define PROC(KX)                                                            \
  {                                                                         \
    v16f s = {};                                                            \
    _Pragma("unroll")                                                       \
    for (int ks = 0; ks < 4; ++ks)                                          \
      s = __builtin_amdgcn_mfma_f32_32x32x16_bf16(qa[ks], KX[ks], s, 0, 0, 0); \
    _Pragma("unroll")                                                       \
    for (int j = 0; j < 16; ++j) {                                          \
      M[j] = fmaxf(M[j], s[j]);                                             \
      S[j] += s[j];                                                         \
    }                                                                       \
  }

  for (int i = 0; i < 32; i += 2) {
    {  // prefetch column i+1 into kB4 (issues before PROC(kA)'s burst)
      const ushort_t* kc = Kb + (size_t)(kq + 4 * (i + 1)) * 2048;
      #pragma unroll
      for (int ks = 0; ks < 4; ++ks)
        kB4[ks] = *(const v8s*)&kc[(ks * 64 + lane) * 8];
    }
    PROC(kA)
    {  // prefetch column i+2 into kA (last pair: harmless re-read of col kq)
      const int c2 = (i + 2 < 32) ? (kq + 4 * (i + 2)) : kq;
      const ushort_t* kc = Kb + (size_t)c2 * 2048;
      #pragma unroll
      for (int ks = 0; ks < 4; ++ks)
        kA[ks] = *(const v8s*)&kc[(ks * 64 + lane) * 8];
    }
    PROC(kB4)
  }
#undef PROC

  // per-row reduce across the 32 key-lanes of this wave's quarter
  #pragma unroll
  for (int j = 0; j < 16; ++j) {
    float Sv = S[j], Mv = M[j];
    Sv += __shfl_xor(Sv, 1);  Mv = fmaxf(Mv, __shfl_xor(Mv, 1));
    Sv += __shfl_xor(Sv, 2);  Mv = fmaxf(Mv, __shfl_xor(Mv, 2));
    Sv += __shfl_xor(Sv, 4);  Mv = fmaxf(Mv, __shfl_xor(Mv, 4));
    Sv += __shfl_xor(Sv, 8);  Mv = fmaxf(Mv, __shfl_xor(Mv, 8));
    Sv += __shfl_xor(Sv, 16); Mv = fmaxf(Mv, __shfl_xor(Mv, 16));
    if (l31 == 0) {
      // C/D 32x32: row = (reg&3)+8*(reg>>2)+4*(lane>>5)  [m74/m101]
      const int row = rs * 32 + (j & 3) + 8 * (j >> 2) + 4 * hi;
      RedS[kq][row] = Sv;
      RedM[kq][row] = Mv;
    }
  }
  __syncthreads();
  if (t < QB) {
    const float Sv = RedS[0][t] + RedS[1][t] + RedS[2][t] + RedS[3][t];
    const float Mv = fmaxf(fmaxf(RedM[0][t], RedM[1][t]),
                           fmaxf(RedM[2][t], RedM[3][t]));
    // Jensen screen (conservative superset of the exact screen, 0.33 slack)
    if (Mv - Sv * (1.0f / 4096.0f) > 8.3f) atomicOr(&bflag, 1);
  }
  __syncthreads();
  if (t == 0) JFlg[lin] = bflag;
}

// ---------------------------------------------------------------------------
// Refine (warm): for Jensen-flagged blocks only (~1 of 1024), compute the
// EXACT per-row screen (exp2-L + M, R8/R10/R13-proven deterministic-cold on
// this data) and write the final flag. Cold blocks write 0 and exit.
// ---------------------------------------------------------------------------
__global__ __launch_bounds__(256) void attn_ref(
    const ushort_t* __restrict__ Qf, const ushort_t* __restrict__ Kf,
    const int* __restrict__ JFlg, int* __restrict__ RFlg)
{
  const int lin = blockIdx.x;
  if (JFlg[lin] == 0) { if (threadIdx.x == 0) RFlg[lin] = 0; return; }
  __shared__ float RedL[4][QB];
  __shared__ float RedM[4][QB];
  __shared__ int bflag;
  const int t = threadIdx.x;
  const int lane = t & 63;
  const int l31 = lane & 31, hi = lane >> 5;
  const int w = t >> 6;           // key quarter
  const int bh = ((lin & 7) << 1) | ((lin >> 3) & 1);
  const int q0 = (lin >> 4) * QB;
  if (t == 0) bflag = 0;

  const size_t hoff = (size_t)bh * (size_t)(S_LEN * HD);
  const ushort_t* Qb = Qf + hoff + (size_t)(q0 >> 5) * 2048;
  const ushort_t* Kb = Kf + hoff;

  v8s qa[4], qB[4];
  #pragma unroll
  for (int ks = 0; ks < 4; ++ks) {
    qa[ks] = *(const v8s*)&Qb[(ks * 64 + lane) * 8];
    qB[ks] = *(const v8s*)&Qb[2048 + (ks * 64 + lane) * 8];
  }

  float L0[16], L1[16], M0[16], M1[16];
  #pragma unroll
  for (int j = 0; j < 16; ++j) {
    L0[j] = 0.f; L1[j] = 0.f; M0[j] = -1e30f; M1[j] = -1e30f;
  }

  for (int i = 0; i < 32; ++i) {
    const ushort_t* kc = Kb + (size_t)(w + 4 * i) * 2048;
    v8s kb[4];
    #pragma unroll
    for (int ks = 0; ks < 4; ++ks)
      kb[ks] = *(const v8s*)&kc[(ks * 64 + lane) * 8];
    v16f sa = {}, sb = {};
    #pragma unroll
    for (int ks = 0; ks < 4; ++ks)
      sa = __builtin_amdgcn_mfma_f32_32x32x16_bf16(qa[ks], kb[ks], sa, 0, 0, 0);
    #pragma unroll
    for (int ks = 0; ks < 4; ++ks)
      sb = __builtin_amdgcn_mfma_f32_32x32x16_bf16(qB[ks], kb[ks], sb, 0, 0, 0);
    #pragma unroll
    for (int j = 0; j < 16; ++j) {
      M0[j] = fmaxf(M0[j], sa[j]);
      L0[j] += fexp2(sa[j]);
    }
    #pragma unroll
    for (int j = 0; j < 16; ++j) {
      M1[j] = fmaxf(M1[j], sb[j]);
      L1[j] += fexp2(sb[j]);
    }
  }

  #pragma unroll
  for (int rseti = 0; rseti < 2; ++rseti)
    #pragma unroll
    for (int j = 0; j < 16; ++j) {
      float Lv = (rseti == 0) ? L0[j] : L1[j];
      float Mv = (rseti == 0) ? M0[j] : M1[j];
      Lv += __shfl_xor(Lv, 1);  Mv = fmaxf(Mv, __shfl_xor(Mv, 1));
      Lv += __shfl_xor(Lv, 2);  Mv = fmaxf(Mv, __shfl_xor(Mv, 2));
      Lv += __shfl_xor(Lv, 4);  Mv = fmaxf(Mv, __shfl_xor(Mv, 4));
      Lv += __shfl_xor(Lv, 8);  Mv = fmaxf(Mv, __shfl_xor(Mv, 8));
      Lv += __shfl_xor(Lv, 16); Mv = fmaxf(Mv, __shfl_xor(Mv, 16));
      if (l31 == 0) {
        const int row = rseti * 32 + (j & 3) + 8 * (j >> 2) + 4 * hi;
        RedL[w][row] = Lv;
        RedM[w][row] = Mv;
      }
    }
  __syncthreads();
  if (t < QB) {
    const float Lv = RedL[0][t] + RedL[1][t] + RedL[2][t] + RedL[3][t];
    const float Mv = fmaxf(fmaxf(RedM[0][t], RedM[1][t]),
                           fmaxf(RedM[2][t], RedM[3][t]));
    // exact per-row screen: p>0.1 possible iff M >= log2(L)+log2(0.1);
    // 0.05 slack, conservative direction
    if (Mv >= __log2f(Lv) - 3.3719281f) atomicOr(&bflag, 1);
  }
  __syncthreads();
  if (t == 0) RFlg[lin] = bflag;
}

// ---------------------------------------------------------------------------
// Attention pass 2 (cold, RFlg-gated): phase A exact per-row L; phase B
// exact p>0.1 threshold + renorm + PV; writes 64-row ctx slice. Never taken
// for this data.
// ---------------------------------------------------------------------------
__global__ __launch_bounds__(256) void attn_p2(
    const ushort_t* __restrict__ Qf, const ushort_t* __restrict__ Kf,
    const ushort_t* __restrict__ V, ushort_t* __restrict__ Cb,
    const int* __restrict__ RFlg)
{
  const int lin = blockIdx.x;
  if (RFlg[lin] == 0) return;
  __shared__ float Osh[QB][HD + 1];
  __shared__ float Dsh[QB];
  __shared__ float RedA[4][QB];
  __shared__ float iLs[QB];
  __shared__ ushort_t Pp[4][32][40];
  __shared__ ushort_t VT[4][HD][40];
  const int t = threadIdx.x;
  const int lane = t & 63;
  const int l31 = lane & 31, hi = lane >> 5;
  const int w = t >> 6;
  const int bh = ((lin & 7) << 1) | ((lin >> 3) & 1);
  const int q0 = (lin >> 4) * QB;
  const size_t hoff = (size_t)bh * (size_t)(S_LEN * HD);
  const ushort_t* Qb = Qf + hoff + (size_t)(q0 >> 5) * 2048;
  const ushort_t* Kb = Kf + hoff;
  const ushort_t* Vh = V + hoff;

  if (t < QB) Dsh[t] = 0.f;
  for (int idx = t; idx < QB * HD; idx += 256) Osh[idx >> 6][idx & 63] = 0.f;

  v8s qa[4], qB[4];
  #pragma unroll
  for (int ks = 0; ks < 4; ++ks) {
    qa[ks] = *(const v8s*)&Qb[(ks * 64 + lane) * 8];
    qB[ks] = *(const v8s*)&Qb[2048 + (ks * 64 + lane) * 8];
  }

  // ---- phase A: exact L per row ----
  float L0[16], L1[16];
  #pragma unroll
  for (int j = 0; j < 16; ++j) { L0[j] = 0.f; L1[j] = 0.f; }
  for (int i = 0; i < 32; ++i) {
    const ushort_t* kc = Kb + (size_t)(w + 4 * i) * 2048;
    v8s kb[4];
    #pragma unroll
    for (int ks = 0; ks < 4; ++ks)
      kb[ks] = *(const v8s*)&kc[(ks * 64 + lane) * 8];
    v16f sa = {}, sb = {};
    #pragma unroll
    for (int ks = 0; ks < 4; ++ks) {
      sa = __builtin_amdgcn_mfma_f32_32x32x16_bf16(qa[ks], kb[ks], sa, 0, 0, 0);
      sb = __builtin_amdgcn_mfma_f32_32x32x16_bf16(qB[ks], kb[ks], sb, 0, 0, 0);
    }
    #pragma unroll
    for (int j = 0; j < 16; ++j) {
      L0[j] += fexp2(sa[j]);
      L1[j] += fexp2(sb[j]);
    }
  }
  #pragma unroll
  for (int rseti = 0; rseti < 2; ++rseti)
    #pragma unroll
    for (int j = 0; j < 16; ++j) {
      float Lv = (rseti == 0) ? L0[j] : L1[j];
      Lv += __shfl_xor(Lv, 1);  Lv += __shfl_xor(Lv, 2);
      Lv += __shfl_xor(Lv, 4);  Lv += __shfl_xor(Lv, 8);
      Lv += __shfl_xor(Lv, 16);
      if (l31 == 0) {
        const int row = rseti * 32 + (j & 3) + 8 * (j >> 2) + 4 * hi;
        RedA[w][row] = Lv;
      }
    }
  __syncthreads();
  if (t < QB)
    iLs[t] = 1.0f / (RedA[0][t] + RedA[1][t] + RedA[2][t] + RedA[3][t]);
  __syncthreads();

  float il[2][16];
  #pragma unroll
  for (int rseti = 0; rseti < 2; ++rseti)
    #pragma unroll
    for (int j = 0; j < 16; ++j)
      il[rseti][j] = iLs[rseti * 32 + (j & 3) + 8 * (j >> 2) + 4 * hi];

  // ---- phase B: threshold + PV ----
  v16f oA[2] = {}, oB[2] = {};
  float den[2][16] = {};

  for (int i = 0; i < 32; ++i) {
    const int c = w + 4 * i;
    const ushort_t* kc = Kb + (size_t)c * 2048;
    v8s kb[4];
    #pragma unroll
    for (int ks = 0; ks < 4; ++ks)
      kb[ks] = *(const v8s*)&kc[(ks * 64 + lane) * 8];
    v16f sa = {}, sb = {};
    #pragma unroll
    for (int ks = 0; ks < 4; ++ks) {
      sa = __builtin_amdgcn_mfma_f32_32x32x16_bf16(qa[ks], kb[ks], sa, 0, 0, 0);
      sb = __builtin_amdgcn_mfma_f32_32x32x16_bf16(qB[ks], kb[ks], sb, 0, 0, 0);
    }
    { // stage V^T for this key column (per-wave private buffer)
      const ushort_t* vsrc = &Vh[((size_t)c * 32 + l31) * HD + hi * 32];
      #pragma unroll
      for (int qq = 0; qq < 4; ++qq) {
        uint4 vv = *(const uint4*)&vsrc[qq * 8];
        const ushort_t* pv = (const ushort_t*)&vv;
        #pragma unroll
        for (int jj = 0; jj < 8; ++jj)
          VT[w][hi * 32 + qq * 8 + jj][l31] = pv[jj];
      }
    }
    #pragma unroll
    for (int rseti = 0; rseti < 2; ++rseti) {
      #pragma unroll
      for (int j = 0; j < 16; ++j) {
        const float s = (rseti == 0) ? sa[j] : sb[j];
        const int row = (j & 3) + 8 * (j >> 2) + 4 * hi;
        float p = fexp2(s) * il[rseti][j];
        p = (p > 0.1f) ? p : 0.f;
        den[rseti][j] += p;
        Pp[w][row][l31] = f2bf(p);       // P[row][key_local]
      }
      // same-wave LDS RAW: compiler orders via lgkmcnt
      v8s pa0 = *(const v8s*)&Pp[w][l31][8 * hi];
      v8s pa1 = *(const v8s*)&Pp[w][l31][16 + 8 * hi];
      #pragma unroll
      for (int dblk = 0; dblk < 2; ++dblk) {
        v8s vb0 = *(const v8s*)&VT[w][dblk * 32 + l31][8 * hi];
        v8s vb1 = *(const v8s*)&VT[w][dblk * 32 + l31][16 + 8 * hi];
        if (rseti == 0) {
          oA[dblk] = __builtin_amdgcn_mfma_f32_32x32x16_bf16(pa0, vb0, oA[dblk], 0, 0, 0);
          oA[dblk] = __builtin_amdgcn_mfma_f32_32x32x16_bf16(pa1, vb1, oA[dblk], 0, 0, 0);
        } else {
          oB[dblk] = __builtin_amdgcn_mfma_f32_32x32x16_bf16(pa0, vb0, oB[dblk], 0, 0, 0);
          oB[dblk] = __builtin_amdgcn_mfma_f32_32x32x16_bf16(pa1, vb1, oB[dblk], 0, 0, 0);
        }
      }
    }
  }

  #pragma unroll
  for (int rseti = 0; rseti < 2; ++rseti)
    #pragma unroll
    for (int j = 0; j < 16; ++j) {
      float d = den[rseti][j];
      d += __shfl_xor(d, 1); d += __shfl_xor(d, 2); d += __shfl_xor(d, 4);
      d += __shfl_xor(d, 8); d += __shfl_xor(d, 16);
      const int row = rseti * 32 + (j & 3) + 8 * (j >> 2) + 4 * hi;
      if (l31 == 0) atomicAdd(&Dsh[row], d);
    }
  #pragma unroll
  for (int rseti = 0; rseti < 2; ++rseti)
    #pragma unroll
    for (int dblk = 0; dblk < 2; ++dblk)
      #pragma unroll
      for (int j = 0; j < 16; ++j) {
        const int row = rseti * 32 + (j & 3) + 8 * (j >> 2) + 4 * hi;
        const float val = (rseti == 0) ? oA[dblk][j] : oB[dblk][j];
        atomicAdd(&Osh[row][dblk * 32 + l31], val);
      }
  __syncthreads();
  const int b = bh >> 3, h = bh & 7;
  for (int idx = t; idx < QB * HD; idx += 256) {
    const int row = idx >> 6, d = idx & 63;
    const float val = Osh[row][d] / (Dsh[row] + 1e-8f);
    Cb[((size_t)b * S_LEN + q0 + row) * HID + h * HD + d] = f2bf(val);
  }
}

// ---------------------------------------------------------------------------
// Output GEMM (bf16 in) with sparsity handling. Per-head flag bitmask from
// RFlg: cold heads' ctx columns staged as ZEROS (Cb never pre-zeroed; only
// p2 writes it). All-cold tile -> out = bias directly. grid (8,128) = 1024.
// ---------------------------------------------------------------------------
__global__ __launch_bounds__(256) void gemm_out(
    const ushort_t* __restrict__ X, const ushort_t* __restrict__ W,
    const float* __restrict__ bias, const int* __restrict__ RFlg,
    float* __restrict__ Df)
{
  const int t = threadIdx.x;
  const int m0 = blockIdx.y * 64;
  const int e0 = blockIdx.x * 64;

  int fm = 0;   // bit h = head h flagged for this 64-row q-block
  {
    const int b = m0 >> 12, qblk = (m0 & (S_LEN - 1)) >> 6;
    #pragma unroll
    for (int h = 0; h < HEADS; ++h) {
      const int bhh = b * HEADS + h;
      const int base = (bhh >> 1) | ((bhh & 1) << 3);
      fm |= (RFlg[base | (qblk << 4)] ? 1 : 0) << h;
    }
    if (!fm) {   // ctx tile is exactly zero -> out = bias
      const int row = t >> 2, c0 = (t & 3) * 16;
      #pragma unroll
      for (int g = 0; g < 4; ++g) {
        const float4 bv = *(const float4*)&bias[e0 + c0 + g * 4];
        *(float4*)&Df[(size_t)(m0 + row) * HID + e0 + c0 + g * 4] = bv;
      }
      return;
    }
  }

  __shared__ ushort_t As[64][40];
  __shared__ ushort_t Bs[64][40];
  const int lane = t & 63;
  const int l15 = lane & 15, lg = lane >> 4;
  const int w = t >> 6;
  const int wr = w >> 1, wc = w & 1;

  v4f acc[2][2] = {};
  const int srow = t >> 2, scol = (t & 3) * 8;
  const uint4 zu = {0u, 0u, 0u, 0u};

  for (int k0 = 0; k0 < HID; k0 += 32) {
    __syncthreads();
    const bool hot = (fm >> (k0 >> 6)) & 1;   // ctx cols k0..k0+31 = head k0/64
    *(uint4*)&As[srow][scol] = hot
        ? *(const uint4*)&X[(size_t)(m0 + srow) * HID + k0 + scol]
        : zu;
    *(uint4*)&Bs[srow][scol] =
        *(const uint4*)&W[(size_t)(e0 + srow) * HID + k0 + scol];
    __syncthreads();
    v8s a[2], b[2];
    #pragma unroll
    for (int fr = 0; fr < 2; ++fr)
      a[fr] = *(const v8s*)&As[wr * 32 + 16 * fr + l15][8 * lg];
    #pragma unroll
    for (int fc = 0; fc < 2; ++fc)
      b[fc] = *(const v8s*)&Bs[wc * 32 + 16 * fc + l15][8 * lg];
    #pragma unroll
    for (int fr = 0; fr < 2; ++fr)
      #pragma unroll
      for (int fc = 0; fc < 2; ++fc)
        acc[fr][fc] = __builtin_amdgcn_mfma_f32_16x16x32_bf16(a[fr], b[fc], acc[fr][fc], 0, 0, 0);
  }

  #pragma unroll
  for (int fr = 0; fr < 2; ++fr)
    #pragma unroll
    for (int fc = 0; fc < 2; ++fc) {
      const int e = e0 + wc * 32 + 16 * fc + l15;
      const float bval = bias[e];
      #pragma unroll
      for (int r = 0; r < 4; ++r) {
        const int m = m0 + wr * 32 + 16 * fr + 4 * lg + r;
        Df[(size_t)m * HID + e] = acc[fr][fc][r] + bval;
      }
    }
}

// ---------------------------------------------------------------------------
extern "C" void kernel_launch(void* const* d_in, const int* in_sizes, int n_in,
                              void* d_out, int out_size, void* d_ws, size_t ws_size,
                              hipStream_t stream) {
  const float* x  = (const float*)d_in[0];
  const float* Wq = (const float*)d_in[1];
  const float* bq = (const float*)d_in[2];
  const float* Wk = (const float*)d_in[3];
  const float* bk = (const float*)d_in[4];
  const float* Wv = (const float*)d_in[5];
  const float* bv = (const float*)d_in[6];
  const float* Wo = (const float*)d_in[7];
  const float* bo = (const float*)d_in[8];

  int*      JFlg = (int*)d_ws;                  // [1024] Jensen flags
  int*      RFlg = JFlg + NBLK;                 // [1024] refined flags
  ushort_t* xb   = (ushort_t*)(RFlg + NBLK);    // bf16 x
  ushort_t* wqb  = xb + NX;                     // 3 QKV weights contiguous
  ushort_t* wob  = wqb + 3 * WSZ;
  ushort_t* Qf   = wob + WSZ;                   // frag-linear
  ushort_t* Kf   = Qf + NX;                     // frag-linear
  ushort_t* Vw   = Kf + NX;                     // plain [B,H,S,HD]
  ushort_t* Cb   = Vw + NX;                     // ctx bf16 (p2-written only)

  const float qscale = 0.125f * 1.44269504f;    // softmax scale * log2(e)

  cvt_k<<<(NX + 4 * WSZ) / 1024, 256, 0, stream>>>(x, Wq, Wk, Wv, Wo, xb);

  gemm_qkv<<<dim3(12, 64), 256, 0, stream>>>(
      xb, wqb, bq, bk, bv, Qf, Kf, Vw, qscale);

  attn_p1<<<NBLK, 512, 0, stream>>>(Qf, Kf, JFlg);
  attn_ref<<<NBLK, 256, 0, stream>>>(Qf, Kf, JFlg, RFlg);
  attn_p2<<<NBLK, 256, 0, stream>>>(Qf, Kf, Vw, Cb, RFlg);

  gemm_out<<<dim3(8, 128), 256, 0, stream>>>(Cb, wob, bo, RFlg, (float*)d_out);
}

// Round 18
// 103.516 us; speedup vs baseline: 1.2408x; 1.2408x over previous
//
#include <hip/hip_runtime.h>

#define S_LEN 4096
#define BATCH 2
#define HID 512
#define HEADS 8
#define HD 64
#define NX (BATCH * S_LEN * HID)       // 4,194,304
#define WSZ (HID * HID)                // 262,144
#define NBH (BATCH * HEADS)            // 16
#define QB 64                          // q rows per attn block
#define NBLK (S_LEN / QB * NBH)        // 1024 blocks / flags

typedef short v8s __attribute__((ext_vector_type(8)));    // 8 bf16
typedef float v4f __attribute__((ext_vector_type(4)));    // 16x16 MFMA acc
typedef float v16f __attribute__((ext_vector_type(16)));  // 32x32 MFMA acc
typedef unsigned short ushort_t;
typedef const __attribute__((address_space(1))) unsigned gu32;
typedef __attribute__((address_space(3))) unsigned lu32;

__device__ __forceinline__ ushort_t f2bf(float f) {       // RNE
  unsigned u = __builtin_bit_cast(unsigned, f);
  u += 0x7fffu + ((u >> 16) & 1u);
  return (ushort_t)(u >> 16);
}
__device__ __forceinline__ unsigned pk2(float a, float b) {  // trunc pack
  return (__builtin_bit_cast(unsigned, a) >> 16) |
         (__builtin_bit_cast(unsigned, b) & 0xFFFF0000u);
}
__device__ __forceinline__ float fexp2(float x) {         // native v_exp_f32
  return __builtin_amdgcn_exp2f(x);
}

// fragment-linear Q/K: per head, per 32-row column (col = s>>5):
// off = col*2048 + ((d>>4)*64 + ((d>>3)&1)*32 + (s&31))*8 + (d&7)
// -> a 32x32x16 MFMA A/B frag (row/col = lane&31, k = 8*(lane>>5)+j) is one
//    v8s load at (kstep*64 + lane)*8: 1KB contiguous per wave instruction.

// ---------------------------------------------------------------------------
// Pre-convert fp32 -> bf16: x then Wq,Wk,Wv,Wo contiguous into dst.
// ---------------------------------------------------------------------------
__global__ __launch_bounds__(256) void cvt_k(
    const float* __restrict__ x,
    const float* __restrict__ wq, const float* __restrict__ wk,
    const float* __restrict__ wv, const float* __restrict__ wo,
    ushort_t* __restrict__ dst)
{
  const size_t e = ((size_t)blockIdx.x * 256 + threadIdx.x) * 4;
  const float* src; size_t off;
  if (e < NX) { src = x; off = e; }
  else {
    const size_t we = e - NX;
    const int wi = (int)(we >> 18);
    src = wi == 0 ? wq : wi == 1 ? wk : wi == 2 ? wv : wo;
    off = we & (WSZ - 1);
  }
  float4 v = *(const float4*)&src[off];
  uint2 u; u.x = pk2(v.x, v.y); u.y = pk2(v.z, v.w);
  *(uint2*)&dst[e] = u;
}

// ---------------------------------------------------------------------------
// QKV GEMM (bf16 in): 128x128 tile, BK=32, 4 waves (2x2), 16x16x32 MFMA.
// Staging via global_load_lds width=16 with BOTH-SIDES chunk swizzle:
//   store: LDS linear dest, global SOURCE col chunk ^= ((row>>1)&3)
//   read : ds_read col = 8*(lg ^ ((l15>>1)&3))
// -> 2 lanes/bank (free) instead of linear layout's 8-way conflict.
// Q,K written frag-linear (Q scaled 0.125*log2e), V plain [B,H,S,HD].
// ---------------------------------------------------------------------------
__global__ __launch_bounds__(256) void gemm_qkv(
    const ushort_t* __restrict__ X, const ushort_t* __restrict__ Wb,
    const float* __restrict__ bq, const float* __restrict__ bk, const float* __restrict__ bv,
    ushort_t* __restrict__ Qf, ushort_t* __restrict__ Kf, ushort_t* __restrict__ Vw,
    float qscale)
{
  __shared__ ushort_t As[128][32];    // linear dest (global_load_lds)
  __shared__ ushort_t Bs[128][32];
  const int t = threadIdx.x;
  const int lane = t & 63;
  const int l15 = lane & 15, lg = lane >> 4;
  const int w = t >> 6;
  const int wr = w >> 1, wc = w & 1;
  const int m0 = blockIdx.y * 128;
  const int wsel = blockIdx.x >> 2;
  const int e0 = (blockIdx.x & 3) * 128;
  const ushort_t* W = Wb + (size_t)wsel * WSZ;
  const float* bias = wsel == 0 ? bq : wsel == 1 ? bk : bv;
  const float osc = (wsel == 0) ? qscale : 1.0f;

  v4f acc[4][4] = {};
  const int r0  = t >> 2;                         // row within rep (0..63)
  const int c0  = (t & 3) * 8;                    // dest col (linear)
  const int sc0 = (((t & 3) ^ ((t >> 3) & 3))) * 8;  // swizzled SOURCE col
  const int rsw = (l15 >> 1) & 3;                 // read-side chunk XOR

  for (int k0 = 0; k0 < HID; k0 += 32) {
    __syncthreads();   // previous tile fully consumed
    __builtin_amdgcn_global_load_lds(
        (gu32*)(const void*)&X[(size_t)(m0 + r0) * HID + k0 + sc0],
        (lu32*)(void*)&As[r0][c0], 16, 0, 0);
    __builtin_amdgcn_global_load_lds(
        (gu32*)(const void*)&X[(size_t)(m0 + r0 + 64) * HID + k0 + sc0],
        (lu32*)(void*)&As[r0 + 64][c0], 16, 0, 0);
    __builtin_amdgcn_global_load_lds(
        (gu32*)(const void*)&W[(size_t)(e0 + r0) * HID + k0 + sc0],
        (lu32*)(void*)&Bs[r0][c0], 16, 0, 0);
    __builtin_amdgcn_global_load_lds(
        (gu32*)(const void*)&W[(size_t)(e0 + r0 + 64) * HID + k0 + sc0],
        (lu32*)(void*)&Bs[r0 + 64][c0], 16, 0, 0);
    __syncthreads();   // drains vmcnt -> LDS tiles ready
    v8s a[4], b[4];
    #pragma unroll
    for (int fr = 0; fr < 4; ++fr)
      a[fr] = *(const v8s*)&As[wr * 64 + 16 * fr + l15][8 * (lg ^ rsw)];
    #pragma unroll
    for (int fc = 0; fc < 4; ++fc)
      b[fc] = *(const v8s*)&Bs[wc * 64 + 16 * fc + l15][8 * (lg ^ rsw)];
    #pragma unroll
    for (int fr = 0; fr < 4; ++fr)
      #pragma unroll
      for (int fc = 0; fc < 4; ++fc)
        acc[fr][fc] = __builtin_amdgcn_mfma_f32_16x16x32_bf16(a[fr], b[fc], acc[fr][fc], 0, 0, 0);
  }

  #pragma unroll
  for (int fr = 0; fr < 4; ++fr)
    #pragma unroll
    for (int fc = 0; fc < 4; ++fc) {
      const int e = e0 + wc * 64 + 16 * fc + l15;
      const float bval = bias[e];
      #pragma unroll
      for (int r = 0; r < 4; ++r) {
        // C/D layout: col = lane&15, row = 4*(lane>>4)+reg  [m89-verified]
        const int m = m0 + wr * 64 + 16 * fr + 4 * lg + r;
        const float v = (acc[fr][fc][r] + bval) * osc;
        const int bidx = m >> 12, s = m & (S_LEN - 1);
        const int hh = e >> 6, dh = e & 63;
        const size_t hb = ((size_t)(bidx * HEADS + hh)) * (size_t)(S_LEN * HD);
        if (wsel == 2) {
          Vw[hb + (size_t)s * HD + dh] = f2bf(v);
        } else {
          const size_t off = (size_t)(s >> 5) * 2048 +
              (size_t)(((dh >> 4) * 64 + ((dh >> 3) & 1) * 32 + (s & 31)) * 8 + (dh & 7));
          (wsel == 0 ? Qf : Kf)[hb + off] = f2bf(v);
        }
      }
    }
}

// ---------------------------------------------------------------------------
// Attention pass 1 (hot): exact PER-ROW screen with DEFERRED-VALU pipeline:
// the previous column's scores (one extra v16f) get their fmax+exp2 MERGE
// issued during the current column's MFMA chain (no dependency -> the two
// pipes overlap instead of serializing). R16 envelope otherwise: 512 thr /
// 8 waves = rowset x key-quarter, 2-deep kA/kB ping-pong, 56+16 VGPR est.
// Tripwire: WRITE_SIZE <= 0.1 MB (spill), VGPR <= ~120.
// ---------------------------------------------------------------------------
__global__ __launch_bounds__(512, 4) void attn_p1(
    const ushort_t* __restrict__ Qf, const ushort_t* __restrict__ Kf,
    int* __restrict__ Flg)
{
  __shared__ float RedL[4][QB];   // [kq][row] partial L
  __shared__ float RedM[4][QB];   // [kq][row] partial max
  __shared__ int bflag;
  const int t = threadIdx.x;
  const int lane = t & 63;
  const int l31 = lane & 31, hi = lane >> 5;
  const int w = t >> 6;           // 0..7
  const int rs = w >> 2;          // rowset (32 q rows each)
  const int kq = w & 3;           // key quarter
  const int lin = blockIdx.x;
  const int bh = ((lin & 7) << 1) | ((lin >> 3) & 1);   // 2 heads per XCD
  const int q0 = (lin >> 4) * QB;
  if (t == 0) bflag = 0;

  const size_t hoff = (size_t)bh * (size_t)(S_LEN * HD);
  const ushort_t* Qb = Qf + hoff + ((size_t)(q0 >> 5) + rs) * 2048;
  const ushort_t* Kb = Kf + hoff;

  v8s qa[4];
  #pragma unroll
  for (int ks = 0; ks < 4; ++ks)
    qa[ks] = *(const v8s*)&Qb[(ks * 64 + lane) * 8];

  float M[16], L[16];
  #pragma unroll
  for (int j = 0; j < 16; ++j) { M[j] = -1e30f; L[j] = 0.f; }

  v8s kA[4], kB[4];

#define LOADK(DST, IDX)                                                     \
  {                                                                         \
    const ushort_t* kc_ = Kb + (size_t)(kq + 4 * (IDX)) * 2048;             \
    _Pragma("unroll")                                                       \
    for (int ks = 0; ks < 4; ++ks)                                          \
      DST[ks] = *(const v8s*)&kc_[(ks * 64 + lane) * 8];                    \
  }
#define CHAIN(KX, OUT)                                                      \
  {                                                                         \
    v16f s_ = {};                                                           \
    _Pragma("unroll")                                                       \
    for (int ks = 0; ks < 4; ++ks)                                          \
      s_ = __builtin_amdgcn_mfma_f32_32x32x16_bf16(qa[ks], KX[ks], s_, 0, 0, 0); \
    OUT = s_;                                                               \
  }
#define MERGE(P)                                                            \
  {                                                                         \
    _Pragma("unroll")                                                       \
    for (int j = 0; j < 16; ++j) {                                          \
      M[j] = fmaxf(M[j], P[j]);                                             \
      L[j] += fexp2(P[j]);                                                  \
    }                                                                       \
  }

  LOADK(kA, 0)
  LOADK(kB, 1)
  v16f prev, cur;
  CHAIN(kA, prev)                      // column 0
  for (int i = 1; i < 31; i += 2) {
    LOADK(kA, i + 1)                   // prefetch next (cols <= 30)
    CHAIN(kB, cur)                     // column i; prev's MERGE overlaps
    MERGE(prev)
    prev = cur;
    LOADK(kB, i + 2)                   // prefetch (cols <= 31)
    CHAIN(kA, cur)                     // column i+1
    MERGE(prev)
    prev = cur;
  }
  CHAIN(kB, cur)                       // column 31
  MERGE(prev)
  MERGE(cur)
#undef LOADK
#undef CHAIN
#undef MERGE

  // per-row reduce across the 32 key-lanes of this wave's quarter
  #pragma unroll
  for (int j = 0; j < 16; ++j) {
    float Lv = L[j], Mv = M[j];
    Lv += __shfl_xor(Lv, 1);  Mv = fmaxf(Mv, __shfl_xor(Mv, 1));
    Lv += __shfl_xor(Lv, 2);  Mv = fmaxf(Mv, __shfl_xor(Mv, 2));
    Lv += __shfl_xor(Lv, 4);  Mv = fmaxf(Mv, __shfl_xor(Mv, 4));
    Lv += __shfl_xor(Lv, 8);  Mv = fmaxf(Mv, __shfl_xor(Mv, 8));
    Lv += __shfl_xor(Lv, 16); Mv = fmaxf(Mv, __shfl_xor(Mv, 16));
    if (l31 == 0) {
      // C/D 32x32: row = (reg&3)+8*(reg>>2)+4*(lane>>5)  [m74/m101]
      const int row = rs * 32 + (j & 3) + 8 * (j >> 2) + 4 * hi;
      RedL[kq][row] = Lv;
      RedM[kq][row] = Mv;
    }
  }
  __syncthreads();
  if (t < QB) {
    const float Lv = RedL[0][t] + RedL[1][t] + RedL[2][t] + RedL[3][t];
    const float Mv = fmaxf(fmaxf(RedM[0][t], RedM[1][t]),
                           fmaxf(RedM[2][t], RedM[3][t]));
    // exact per-row screen: p>0.1 possible iff M >= log2(L)+log2(0.1);
    // 0.05 slack, conservative direction (R8/R10/R13/R14/R16-proven cold)
    if (Mv >= __log2f(Lv) - 3.3719281f) atomicOr(&bflag, 1);
  }
  __syncthreads();
  if (t == 0) Flg[lin] = bflag;
}

// ---------------------------------------------------------------------------
// Attention pass 2 (cold, Flg-gated): phase A exact per-row L; phase B exact
// p>0.1 threshold + renorm + PV; writes 64-row ctx slice. Never taken for
// this data.
// ---------------------------------------------------------------------------
__global__ __launch_bounds__(256) void attn_p2(
    const ushort_t* __restrict__ Qf, const ushort_t* __restrict__ Kf,
    const ushort_t* __restrict__ V, ushort_t* __restrict__ Cb,
    const int* __restrict__ Flg)
{
  const int lin = blockIdx.x;
  if (Flg[lin] == 0) return;
  __shared__ float Osh[QB][HD + 1];
  __shared__ float Dsh[QB];
  __shared__ float RedA[4][QB];
  __shared__ float iLs[QB];
  __shared__ ushort_t Pp[4][32][40];
  __shared__ ushort_t VT[4][HD][40];
  const int t = threadIdx.x;
  const int lane = t & 63;
  const int l31 = lane & 31, hi = lane >> 5;
  const int w = t >> 6;
  const int bh = ((lin & 7) << 1) | ((lin >> 3) & 1);
  const int q0 = (lin >> 4) * QB;
  const size_t hoff = (size_t)bh * (size_t)(S_LEN * HD);
  const ushort_t* Qb = Qf + hoff + (size_t)(q0 >> 5) * 2048;
  const ushort_t* Kb = Kf + hoff;
  const ushort_t* Vh = V + hoff;

  if (t < QB) Dsh[t] = 0.f;
  for (int idx = t; idx < QB * HD; idx += 256) Osh[idx >> 6][idx & 63] = 0.f;

  v8s qa[4], qB[4];
  #pragma unroll
  for (int ks = 0; ks < 4; ++ks) {
    qa[ks] = *(const v8s*)&Qb[(ks * 64 + lane) * 8];
    qB[ks] = *(const v8s*)&Qb[2048 + (ks * 64 + lane) * 8];
  }

  // ---- phase A: exact L per row ----
  float L0[16], L1[16];
  #pragma unroll
  for (int j = 0; j < 16; ++j) { L0[j] = 0.f; L1[j] = 0.f; }
  for (int i = 0; i < 32; ++i) {
    const ushort_t* kc = Kb + (size_t)(w + 4 * i) * 2048;
    v8s kb[4];
    #pragma unroll
    for (int ks = 0; ks < 4; ++ks)
      kb[ks] = *(const v8s*)&kc[(ks * 64 + lane) * 8];
    v16f sa = {}, sb = {};
    #pragma unroll
    for (int ks = 0; ks < 4; ++ks) {
      sa = __builtin_amdgcn_mfma_f32_32x32x16_bf16(qa[ks], kb[ks], sa, 0, 0, 0);
      sb = __builtin_amdgcn_mfma_f32_32x32x16_bf16(qB[ks], kb[ks], sb, 0, 0, 0);
    }
    #pragma unroll
    for (int j = 0; j < 16; ++j) {
      L0[j] += fexp2(sa[j]);
      L1[j] += fexp2(sb[j]);
    }
  }
  #pragma unroll
  for (int rseti = 0; rseti < 2; ++rseti)
    #pragma unroll
    for (int j = 0; j < 16; ++j) {
      float Lv = (rseti == 0) ? L0[j] : L1[j];
      Lv += __shfl_xor(Lv, 1);  Lv += __shfl_xor(Lv, 2);
      Lv += __shfl_xor(Lv, 4);  Lv += __shfl_xor(Lv, 8);
      Lv += __shfl_xor(Lv, 16);
      if (l31 == 0) {
        const int row = rseti * 32 + (j & 3) + 8 * (j >> 2) + 4 * hi;
        RedA[w][row] = Lv;
      }
    }
  __syncthreads();
  if (t < QB)
    iLs[t] = 1.0f / (RedA[0][t] + RedA[1][t] + RedA[2][t] + RedA[3][t]);
  __syncthreads();

  float il[2][16];
  #pragma unroll
  for (int rseti = 0; rseti < 2; ++rseti)
    #pragma unroll
    for (int j = 0; j < 16; ++j)
      il[rseti][j] = iLs[rseti * 32 + (j & 3) + 8 * (j >> 2) + 4 * hi];

  // ---- phase B: threshold + PV ----
  v16f oA[2] = {}, oB[2] = {};
  float den[2][16] = {};

  for (int i = 0; i < 32; ++i) {
    const int c = w + 4 * i;
    const ushort_t* kc = Kb + (size_t)c * 2048;
    v8s kb[4];
    #pragma unroll
    for (int ks = 0; ks < 4; ++ks)
      kb[ks] = *(const v8s*)&kc[(ks * 64 + lane) * 8];
    v16f sa = {}, sb = {};
    #pragma unroll
    for (int ks = 0; ks < 4; ++ks) {
      sa = __builtin_amdgcn_mfma_f32_32x32x16_bf16(qa[ks], kb[ks], sa, 0, 0, 0);
      sb = __builtin_amdgcn_mfma_f32_32x32x16_bf16(qB[ks], kb[ks], sb, 0, 0, 0);
    }
    { // stage V^T for this key column (per-wave private buffer)
      const ushort_t* vsrc = &Vh[((size_t)c * 32 + l31) * HD + hi * 32];
      #pragma unroll
      for (int qq = 0; qq < 4; ++qq) {
        uint4 vv = *(const uint4*)&vsrc[qq * 8];
        const ushort_t* pv = (const ushort_t*)&vv;
        #pragma unroll
        for (int jj = 0; jj < 8; ++jj)
          VT[w][hi * 32 + qq * 8 + jj][l31] = pv[jj];
      }
    }
    #pragma unroll
    for (int rseti = 0; rseti < 2; ++rseti) {
      #pragma unroll
      for (int j = 0; j < 16; ++j) {
        const float s = (rseti == 0) ? sa[j] : sb[j];
        const int row = (j & 3) + 8 * (j >> 2) + 4 * hi;
        float p = fexp2(s) * il[rseti][j];
        p = (p > 0.1f) ? p : 0.f;
        den[rseti][j] += p;
        Pp[w][row][l31] = f2bf(p);       // P[row][key_local]
      }
      // same-wave LDS RAW: compiler orders via lgkmcnt
      v8s pa0 = *(const v8s*)&Pp[w][l31][8 * hi];
      v8s pa1 = *(const v8s*)&Pp[w][l31][16 + 8 * hi];
      #pragma unroll
      for (int dblk = 0; dblk < 2; ++dblk) {
        v8s vb0 = *(const v8s*)&VT[w][dblk * 32 + l31][8 * hi];
        v8s vb1 = *(const v8s*)&VT[w][dblk * 32 + l31][16 + 8 * hi];
        if (rseti == 0) {
          oA[dblk] = __builtin_amdgcn_mfma_f32_32x32x16_bf16(pa0, vb0, oA[dblk], 0, 0, 0);
          oA[dblk] = __builtin_amdgcn_mfma_f32_32x32x16_bf16(pa1, vb1, oA[dblk], 0, 0, 0);
        } else {
          oB[dblk] = __builtin_amdgcn_mfma_f32_32x32x16_bf16(pa0, vb0, oB[dblk], 0, 0, 0);
          oB[dblk] = __builtin_amdgcn_mfma_f32_32x32x16_bf16(pa1, vb1, oB[dblk], 0, 0, 0);
        }
      }
    }
  }

  #pragma unroll
  for (int rseti = 0; rseti < 2; ++rseti)
    #pragma unroll
    for (int j = 0; j < 16; ++j) {
      float d = den[rseti][j];
      d += __shfl_xor(d, 1); d += __shfl_xor(d, 2); d += __shfl_xor(d, 4);
      d += __shfl_xor(d, 8); d += __shfl_xor(d, 16);
      const int row = rseti * 32 + (j & 3) + 8 * (j >> 2) + 4 * hi;
      if (l31 == 0) atomicAdd(&Dsh[row], d);
    }
  #pragma unroll
  for (int rseti = 0; rseti < 2; ++rseti)
    #pragma unroll
    for (int dblk = 0; dblk < 2; ++dblk)
      #pragma unroll
      for (int j = 0; j < 16; ++j) {
        const int row = rseti * 32 + (j & 3) + 8 * (j >> 2) + 4 * hi;
        const float val = (rseti == 0) ? oA[dblk][j] : oB[dblk][j];
        atomicAdd(&Osh[row][dblk * 32 + l31], val);
      }
  __syncthreads();
  const int b = bh >> 3, h = bh & 7;
  for (int idx = t; idx < QB * HD; idx += 256) {
    const int row = idx >> 6, d = idx & 63;
    const float val = Osh[row][d] / (Dsh[row] + 1e-8f);
    Cb[((size_t)b * S_LEN + q0 + row) * HID + h * HD + d] = f2bf(val);
  }
}

// ---------------------------------------------------------------------------
// Output GEMM (bf16 in) with sparsity handling. Per-head flag bitmask:
// cold heads' ctx columns staged as ZEROS (Cb never pre-zeroed; only p2
// writes it). All-cold tile -> out = bias directly. grid (8,128) = 1024.
// ---------------------------------------------------------------------------
__global__ __launch_bounds__(256) void gemm_out(
    const ushort_t* __restrict__ X, const ushort_t* __restrict__ W,
    const float* __restrict__ bias, const int* __restrict__ Flg,
    float* __restrict__ Df)
{
  const int t = threadIdx.x;
  const int m0 = blockIdx.y * 64;
  const int e0 = blockIdx.x * 64;

  int fm = 0;   // bit h = head h flagged for this 64-row q-block
  {
    const int b = m0 >> 12, qblk = (m0 & (S_LEN - 1)) >> 6;
    #pragma unroll
    for (int h = 0; h < HEADS; ++h) {
      const int bhh = b * HEADS + h;
      const int base = (bhh >> 1) | ((bhh & 1) << 3);
      fm |= (Flg[base | (qblk << 4)] ? 1 : 0) << h;
    }
    if (!fm) {   // ctx tile is exactly zero -> out = bias
      const int row = t >> 2, c0 = (t & 3) * 16;
      #pragma unroll
      for (int g = 0; g < 4; ++g) {
        const float4 bv = *(const float4*)&bias[e0 + c0 + g * 4];
        *(float4*)&Df[(size_t)(m0 + row) * HID + e0 + c0 + g * 4] = bv;
      }
      return;
    }
  }

  __shared__ ushort_t As[64][40];
  __shared__ ushort_t Bs[64][40];
  const int lane = t & 63;
  const int l15 = lane & 15, lg = lane >> 4;
  const int w = t >> 6;
  const int wr = w >> 1, wc = w & 1;

  v4f acc[2][2] = {};
  const int srow = t >> 2, scol = (t & 3) * 8;
  const uint4 zu = {0u, 0u, 0u, 0u};

  for (int k0 = 0; k0 < HID; k0 += 32) {
    __syncthreads();
    const bool hot = (fm >> (k0 >> 6)) & 1;   // ctx cols k0..k0+31 = head k0/64
    *(uint4*)&As[srow][scol] = hot
        ? *(const uint4*)&X[(size_t)(m0 + srow) * HID + k0 + scol]
        : zu;
    *(uint4*)&Bs[srow][scol] =
        *(const uint4*)&W[(size_t)(e0 + srow) * HID + k0 + scol];
    __syncthreads();
    v8s a[2], b[2];
    #pragma unroll
    for (int fr = 0; fr < 2; ++fr)
      a[fr] = *(const v8s*)&As[wr * 32 + 16 * fr + l15][8 * lg];
    #pragma unroll
    for (int fc = 0; fc < 2; ++fc)
      b[fc] = *(const v8s*)&Bs[wc * 32 + 16 * fc + l15][8 * lg];
    #pragma unroll
    for (int fr = 0; fr < 2; ++fr)
      #pragma unroll
      for (int fc = 0; fc < 2; ++fc)
        acc[fr][fc] = __builtin_amdgcn_mfma_f32_16x16x32_bf16(a[fr], b[fc], acc[fr][fc], 0, 0, 0);
  }

  #pragma unroll
  for (int fr = 0; fr < 2; ++fr)
    #pragma unroll
    for (int fc = 0; fc < 2; ++fc) {
      const int e = e0 + wc * 32 + 16 * fc + l15;
      const float bval = bias[e];
      #pragma unroll
      for (int r = 0; r < 4; ++r) {
        const int m = m0 + wr * 32 + 16 * fr + 4 * lg + r;
        Df[(size_t)m * HID + e] = acc[fr][fc][r] + bval;
      }
    }
}

// ---------------------------------------------------------------------------
extern "C" void kernel_launch(void* const* d_in, const int* in_sizes, int n_in,
                              void* d_out, int out_size, void* d_ws, size_t ws_size,
                              hipStream_t stream) {
  const float* x  = (const float*)d_in[0];
  const float* Wq = (const float*)d_in[1];
  const float* bq = (const float*)d_in[2];
  const float* Wk = (const float*)d_in[3];
  const float* bk = (const float*)d_in[4];
  const float* Wv = (const float*)d_in[5];
  const float* bv = (const float*)d_in[6];
  const float* Wo = (const float*)d_in[7];
  const float* bo = (const float*)d_in[8];

  int*      Flg  = (int*)d_ws;                  // [1024]
  ushort_t* xb   = (ushort_t*)(Flg + NBLK);     // bf16 x
  ushort_t* wqb  = xb + NX;                     // 3 QKV weights contiguous
  ushort_t* wob  = wqb + 3 * WSZ;
  ushort_t* Qf   = wob + WSZ;                   // frag-linear
  ushort_t* Kf   = Qf + NX;                     // frag-linear
  ushort_t* Vw   = Kf + NX;                     // plain [B,H,S,HD]
  ushort_t* Cb   = Vw + NX;                     // ctx bf16 (p2-written only)

  const float qscale = 0.125f * 1.44269504f;    // softmax scale * log2(e)

  cvt_k<<<(NX + 4 * WSZ) / 1024, 256, 0, stream>>>(x, Wq, Wk, Wv, Wo, xb);

  gemm_qkv<<<dim3(12, 64), 256, 0, stream>>>(
      xb, wqb, bq, bk, bv, Qf, Kf, Vw, qscale);

  attn_p1<<<NBLK, 512, 0, stream>>>(Qf, Kf, Flg);
  attn_p2<<<NBLK, 256, 0, stream>>>(Qf, Kf, Vw, Cb, Flg);

  gemm_out<<<dim3(8, 128), 256, 0, stream>>>(Cb, wob, bo, Flg, (float*)d_out);
}

// Round 19
// 96.244 us; speedup vs baseline: 1.3346x; 1.0756x over previous
//
#include <hip/hip_runtime.h>

#define S_LEN 4096
#define BATCH 2
#define HID 512
#define HEADS 8
#define HD 64
#define NX (BATCH * S_LEN * HID)       // 4,194,304
#define WSZ (HID * HID)                // 262,144
#define NBH (BATCH * HEADS)            // 16
#define QB 64                          // q rows per attn block
#define NBLK (S_LEN / QB * NBH)        // 1024 blocks / flags

typedef short v8s __attribute__((ext_vector_type(8)));    // 8 bf16
typedef float v4f __attribute__((ext_vector_type(4)));    // 16x16 MFMA acc
typedef float v16f __attribute__((ext_vector_type(16)));  // 32x32 MFMA acc
typedef unsigned short ushort_t;
typedef const __attribute__((address_space(1))) unsigned gu32;
typedef __attribute__((address_space(3))) unsigned lu32;

__device__ __forceinline__ ushort_t f2bf(float f) {       // RNE
  unsigned u = __builtin_bit_cast(unsigned, f);
  u += 0x7fffu + ((u >> 16) & 1u);
  return (ushort_t)(u >> 16);
}
__device__ __forceinline__ unsigned pk2(float a, float b) {  // trunc pack
  return (__builtin_bit_cast(unsigned, a) >> 16) |
         (__builtin_bit_cast(unsigned, b) & 0xFFFF0000u);
}
__device__ __forceinline__ float fexp2(float x) {         // native v_exp_f32
  return __builtin_amdgcn_exp2f(x);
}

// fragment-linear-16 Q/K: per head,
//   off16(s,d) = (s>>4)*1024 + (d>>5)*512 + ((s&15)+16*((d>>3)&3))*8 + (d&7)
// -> a 16x16x32 MFMA A/B frag (row = lane&15, kslot = 8*(lane>>4)+j over one
//    32-d step) is ONE v8s load at col*1024 + ds*512 + lane*8 (1KB/wave).
// QK^T is invariant to the kslot->d permutation (A and B share the map).
__device__ __forceinline__ size_t off16(int s, int d) {
  return (size_t)(s >> 4) * 1024 +
         (size_t)((d >> 5) * 512 + (((s & 15) + 16 * ((d >> 3) & 3)) * 8) + (d & 7));
}

// ---------------------------------------------------------------------------
// Pre-convert fp32 -> bf16: x then Wq,Wk,Wv,Wo contiguous into dst.
// ---------------------------------------------------------------------------
__global__ __launch_bounds__(256) void cvt_k(
    const float* __restrict__ x,
    const float* __restrict__ wq, const float* __restrict__ wk,
    const float* __restrict__ wv, const float* __restrict__ wo,
    ushort_t* __restrict__ dst)
{
  const size_t e = ((size_t)blockIdx.x * 256 + threadIdx.x) * 4;
  const float* src; size_t off;
  if (e < NX) { src = x; off = e; }
  else {
    const size_t we = e - NX;
    const int wi = (int)(we >> 18);
    src = wi == 0 ? wq : wi == 1 ? wk : wi == 2 ? wv : wo;
    off = we & (WSZ - 1);
  }
  float4 v = *(const float4*)&src[off];
  uint2 u; u.x = pk2(v.x, v.y); u.y = pk2(v.z, v.w);
  *(uint2*)&dst[e] = u;
}

// ---------------------------------------------------------------------------
// QKV GEMM (bf16 in): 128x128 tile, BK=32, 4 waves (2x2), 16x16x32 MFMA.
// Staging via global_load_lds width=16 with BOTH-SIDES chunk swizzle (R18):
//   store: LDS linear dest, global SOURCE col chunk ^= ((row>>1)&3)
//   read : ds_read col = 8*(lg ^ ((l15>>1)&3))
// Q,K written frag-linear-16 (Q scaled 0.125*log2e), V plain [B,H,S,HD].
// ---------------------------------------------------------------------------
__global__ __launch_bounds__(256) void gemm_qkv(
    const ushort_t* __restrict__ X, const ushort_t* __restrict__ Wb,
    const float* __restrict__ bq, const float* __restrict__ bk, const float* __restrict__ bv,
    ushort_t* __restrict__ Qf, ushort_t* __restrict__ Kf, ushort_t* __restrict__ Vw,
    float qscale)
{
  __shared__ ushort_t As[128][32];    // linear dest (global_load_lds)
  __shared__ ushort_t Bs[128][32];
  const int t = threadIdx.x;
  const int lane = t & 63;
  const int l15 = lane & 15, lg = lane >> 4;
  const int w = t >> 6;
  const int wr = w >> 1, wc = w & 1;
  const int m0 = blockIdx.y * 128;
  const int wsel = blockIdx.x >> 2;
  const int e0 = (blockIdx.x & 3) * 128;
  const ushort_t* W = Wb + (size_t)wsel * WSZ;
  const float* bias = wsel == 0 ? bq : wsel == 1 ? bk : bv;
  const float osc = (wsel == 0) ? qscale : 1.0f;

  v4f acc[4][4] = {};
  const int r0  = t >> 2;                            // row within rep (0..63)
  const int c0  = (t & 3) * 8;                       // dest col (linear)
  const int sc0 = (((t & 3) ^ ((t >> 3) & 3))) * 8;  // swizzled SOURCE col
  const int rsw = (l15 >> 1) & 3;                    // read-side chunk XOR

  for (int k0 = 0; k0 < HID; k0 += 32) {
    __syncthreads();   // previous tile fully consumed
    __builtin_amdgcn_global_load_lds(
        (gu32*)(const void*)&X[(size_t)(m0 + r0) * HID + k0 + sc0],
        (lu32*)(void*)&As[r0][c0], 16, 0, 0);
    __builtin_amdgcn_global_load_lds(
        (gu32*)(const void*)&X[(size_t)(m0 + r0 + 64) * HID + k0 + sc0],
        (lu32*)(void*)&As[r0 + 64][c0], 16, 0, 0);
    __builtin_amdgcn_global_load_lds(
        (gu32*)(const void*)&W[(size_t)(e0 + r0) * HID + k0 + sc0],
        (lu32*)(void*)&Bs[r0][c0], 16, 0, 0);
    __builtin_amdgcn_global_load_lds(
        (gu32*)(const void*)&W[(size_t)(e0 + r0 + 64) * HID + k0 + sc0],
        (lu32*)(void*)&Bs[r0 + 64][c0], 16, 0, 0);
    __syncthreads();   // drains vmcnt -> LDS tiles ready
    v8s a[4], b[4];
    #pragma unroll
    for (int fr = 0; fr < 4; ++fr)
      a[fr] = *(const v8s*)&As[wr * 64 + 16 * fr + l15][8 * (lg ^ rsw)];
    #pragma unroll
    for (int fc = 0; fc < 4; ++fc)
      b[fc] = *(const v8s*)&Bs[wc * 64 + 16 * fc + l15][8 * (lg ^ rsw)];
    #pragma unroll
    for (int fr = 0; fr < 4; ++fr)
      #pragma unroll
      for (int fc = 0; fc < 4; ++fc)
        acc[fr][fc] = __builtin_amdgcn_mfma_f32_16x16x32_bf16(a[fr], b[fc], acc[fr][fc], 0, 0, 0);
  }

  #pragma unroll
  for (int fr = 0; fr < 4; ++fr)
    #pragma unroll
    for (int fc = 0; fc < 4; ++fc) {
      const int e = e0 + wc * 64 + 16 * fc + l15;
      const float bval = bias[e];
      #pragma unroll
      for (int r = 0; r < 4; ++r) {
        // C/D layout: col = lane&15, row = 4*(lane>>4)+reg  [m89-verified]
        const int m = m0 + wr * 64 + 16 * fr + 4 * lg + r;
        const float v = (acc[fr][fc][r] + bval) * osc;
        const int bidx = m >> 12, s = m & (S_LEN - 1);
        const int hh = e >> 6, dh = e & 63;
        const size_t hb = ((size_t)(bidx * HEADS + hh)) * (size_t)(S_LEN * HD);
        if (wsel == 2) {
          Vw[hb + (size_t)s * HD + dh] = f2bf(v);
        } else {
          (wsel == 0 ? Qf : Kf)[hb + off16(s, dh)] = f2bf(v);
        }
      }
    }
}

// ---------------------------------------------------------------------------
// Attention pass 1 (hot): exact PER-ROW screen, 16x16x32 MFMA tiles.
// Per iter: 2x2 grid of 16x16 tiles = 8 MFMAs in 4 INDEPENDENT depth-2
// chains (vs 32x32's single depth-4 chain) -> ~3x shorter critical path +
// real ILP. Deferred MERGE (R18): previous iter's acc merged during current
// MFMAs. 512 thr / 8 waves = rowset x key-quarter; 2-deep kA/kB ping-pong.
// State: qa 16 + kA/kB 32 + M/L 16 + acc 2x16 -> <= R18's 64 VGPR class.
// Tripwire: WRITE_SIZE <= 0.1 MB, VGPR <= ~96.
// ---------------------------------------------------------------------------
__global__ __launch_bounds__(512, 4) void attn_p1(
    const ushort_t* __restrict__ Qf, const ushort_t* __restrict__ Kf,
    int* __restrict__ Flg)
{
  __shared__ float RedL[4][QB];   // [kq][row] partial L
  __shared__ float RedM[4][QB];   // [kq][row] partial max
  __shared__ int bflag;
  const int t = threadIdx.x;
  const int lane = t & 63;
  const int l15 = lane & 15, lg = (lane >> 4) & 3;
  const int w = t >> 6;           // 0..7
  const int rs = w >> 2;          // rowset (32 q rows each)
  const int kq = w & 3;           // key quarter
  const int lin = blockIdx.x;
  const int bh = ((lin & 7) << 1) | ((lin >> 3) & 1);   // 2 heads per XCD
  const int q0 = (lin >> 4) * QB;
  if (t == 0) bflag = 0;

  const size_t hoff = (size_t)bh * (size_t)(S_LEN * HD);
  const ushort_t* Qb = Qf + hoff;
  const ushort_t* Kb = Kf + hoff;

  // Q frags: 2 row-tiles (16 rows each) x 2 d-steps
  v8s qa[2][2];
  const int qc0 = (q0 >> 4) + rs * 2;
  #pragma unroll
  for (int tq = 0; tq < 2; ++tq)
    #pragma unroll
    for (int ds = 0; ds < 2; ++ds)
      qa[tq][ds] = *(const v8s*)&Qb[(size_t)(qc0 + tq) * 1024 + ds * 512 + lane * 8];

  float M[2][4], L[2][4];
  #pragma unroll
  for (int tq = 0; tq < 2; ++tq)
    #pragma unroll
    for (int r = 0; r < 4; ++r) { M[tq][r] = -1e30f; L[tq][r] = 0.f; }

  v8s kA[2][2], kB[2][2];

#define LOADK(DST, IDX)                                                     \
  {                                                                         \
    const int kc_ = (kq + 4 * (IDX)) * 2;                                   \
    _Pragma("unroll")                                                       \
    for (int tk = 0; tk < 2; ++tk)                                          \
      _Pragma("unroll")                                                     \
      for (int ds = 0; ds < 2; ++ds)                                        \
        DST[tk][ds] = *(const v8s*)&Kb[(size_t)(kc_ + tk) * 1024 + ds * 512 + lane * 8]; \
  }
#define CHAIN(KX, OUT)                                                      \
  {                                                                         \
    _Pragma("unroll")                                                       \
    for (int tq = 0; tq < 2; ++tq)                                          \
      _Pragma("unroll")                                                     \
      for (int tk = 0; tk < 2; ++tk) {                                      \
        v4f s_ = {0.f, 0.f, 0.f, 0.f};                                      \
        s_ = __builtin_amdgcn_mfma_f32_16x16x32_bf16(qa[tq][0], KX[tk][0], s_, 0, 0, 0); \
        s_ = __builtin_amdgcn_mfma_f32_16x16x32_bf16(qa[tq][1], KX[tk][1], s_, 0, 0, 0); \
        OUT[tq][tk] = s_;                                                   \
      }                                                                     \
  }
#define MERGE(P)                                                            \
  {                                                                         \
    _Pragma("unroll")                                                       \
    for (int tq = 0; tq < 2; ++tq)                                          \
      _Pragma("unroll")                                                     \
      for (int tk = 0; tk < 2; ++tk)                                        \
        _Pragma("unroll")                                                   \
        for (int r = 0; r < 4; ++r) {                                       \
          M[tq][r] = fmaxf(M[tq][r], P[tq][tk][r]);                         \
          L[tq][r] += fexp2(P[tq][tk][r]);                                  \
        }                                                                   \
  }
#define CPY(D, S)                                                           \
  {                                                                         \
    _Pragma("unroll")                                                       \
    for (int tq = 0; tq < 2; ++tq)                                          \
      _Pragma("unroll")                                                     \
      for (int tk = 0; tk < 2; ++tk) D[tq][tk] = S[tq][tk];                 \
  }

  LOADK(kA, 0)
  LOADK(kB, 1)
  v4f prev[2][2], cur[2][2];
  CHAIN(kA, prev)                      // column block 0
  for (int i = 1; i < 31; i += 2) {
    LOADK(kA, i + 1)                   // prefetch next
    CHAIN(kB, cur)                     // block i; prev's MERGE overlaps
    MERGE(prev)
    CPY(prev, cur)
    LOADK(kB, i + 2)
    CHAIN(kA, cur)                     // block i+1
    MERGE(prev)
    CPY(prev, cur)
  }
  CHAIN(kB, cur)                       // block 31
  MERGE(prev)
  MERGE(cur)
#undef LOADK
#undef CHAIN
#undef MERGE
#undef CPY

  // reduce across the 16 key-lanes (l15) of this wave's quarter
  #pragma unroll
  for (int tq = 0; tq < 2; ++tq)
    #pragma unroll
    for (int r = 0; r < 4; ++r) {
      float Lv = L[tq][r], Mv = M[tq][r];
      Lv += __shfl_xor(Lv, 1);  Mv = fmaxf(Mv, __shfl_xor(Mv, 1));
      Lv += __shfl_xor(Lv, 2);  Mv = fmaxf(Mv, __shfl_xor(Mv, 2));
      Lv += __shfl_xor(Lv, 4);  Mv = fmaxf(Mv, __shfl_xor(Mv, 4));
      Lv += __shfl_xor(Lv, 8);  Mv = fmaxf(Mv, __shfl_xor(Mv, 8));
      if (l15 == 0) {
        // 16x16 C/D: col = lane&15, row = 4*(lane>>4)+reg  [m89-verified]
        const int row = rs * 32 + tq * 16 + 4 * lg + r;
        RedL[kq][row] = Lv;
        RedM[kq][row] = Mv;
      }
    }
  __syncthreads();
  if (t < QB) {
    const float Lv = RedL[0][t] + RedL[1][t] + RedL[2][t] + RedL[3][t];
    const float Mv = fmaxf(fmaxf(RedM[0][t], RedM[1][t]),
                           fmaxf(RedM[2][t], RedM[3][t]));
    // exact per-row screen: p>0.1 possible iff M >= log2(L)+log2(0.1);
    // 0.05 slack, conservative direction (R8..R18-proven cold)
    if (Mv >= __log2f(Lv) - 3.3719281f) atomicOr(&bflag, 1);
  }
  __syncthreads();
  if (t == 0) Flg[lin] = bflag;
}

// ---------------------------------------------------------------------------
// Attention pass 2 (cold, Flg-gated): 32x32 MFMA structure retained; Q/K
// fragments gathered element-wise via off16 (cold path, scalar loads fine).
// Phase A exact per-row L; phase B exact p>0.1 threshold + renorm + PV.
// Never taken for this data.
// ---------------------------------------------------------------------------
__global__ __launch_bounds__(256) void attn_p2(
    const ushort_t* __restrict__ Qf, const ushort_t* __restrict__ Kf,
    const ushort_t* __restrict__ V, ushort_t* __restrict__ Cb,
    const int* __restrict__ Flg)
{
  const int lin = blockIdx.x;
  if (Flg[lin] == 0) return;
  __shared__ float Osh[QB][HD + 1];
  __shared__ float Dsh[QB];
  __shared__ float RedA[4][QB];
  __shared__ float iLs[QB];
  __shared__ ushort_t Pp[4][32][40];
  __shared__ ushort_t VT[4][HD][40];
  const int t = threadIdx.x;
  const int lane = t & 63;
  const int l31 = lane & 31, hi = lane >> 5;
  const int w = t >> 6;
  const int bh = ((lin & 7) << 1) | ((lin >> 3) & 1);
  const int q0 = (lin >> 4) * QB;
  const size_t hoff = (size_t)bh * (size_t)(S_LEN * HD);
  const ushort_t* Qb = Qf + hoff;
  const ushort_t* Kb = Kf + hoff;
  const ushort_t* Vh = V + hoff;

  if (t < QB) Dsh[t] = 0.f;
  for (int idx = t; idx < QB * HD; idx += 256) Osh[idx >> 6][idx & 63] = 0.f;

  // 32x32 A-frag gather via off16: row = lane&31, d = ks*16 + 8*hi + j
#define LD32(DST, BASE, SROW, KS)                                           \
  { ushort_t tmp_[8];                                                       \
    _Pragma("unroll")                                                       \
    for (int j_ = 0; j_ < 8; ++j_)                                          \
      tmp_[j_] = BASE[off16((SROW), (KS) * 16 + 8 * hi + j_)];              \
    DST = *(const v8s*)tmp_; }

  v8s qa[4], qB[4];
  #pragma unroll
  for (int ks = 0; ks < 4; ++ks) {
    LD32(qa[ks], Qb, q0 + l31, ks)
    LD32(qB[ks], Qb, q0 + 32 + l31, ks)
  }

  // ---- phase A: exact L per row ----
  float L0[16], L1[16];
  #pragma unroll
  for (int j = 0; j < 16; ++j) { L0[j] = 0.f; L1[j] = 0.f; }
  for (int i = 0; i < 32; ++i) {
    const int c = w + 4 * i;
    v8s kb[4];
    #pragma unroll
    for (int ks = 0; ks < 4; ++ks)
      LD32(kb[ks], Kb, c * 32 + l31, ks)
    v16f sa = {}, sb = {};
    #pragma unroll
    for (int ks = 0; ks < 4; ++ks) {
      sa = __builtin_amdgcn_mfma_f32_32x32x16_bf16(qa[ks], kb[ks], sa, 0, 0, 0);
      sb = __builtin_amdgcn_mfma_f32_32x32x16_bf16(qB[ks], kb[ks], sb, 0, 0, 0);
    }
    #pragma unroll
    for (int j = 0; j < 16; ++j) {
      L0[j] += fexp2(sa[j]);
      L1[j] += fexp2(sb[j]);
    }
  }
  #pragma unroll
  for (int rseti = 0; rseti < 2; ++rseti)
    #pragma unroll
    for (int j = 0; j < 16; ++j) {
      float Lv = (rseti == 0) ? L0[j] : L1[j];
      Lv += __shfl_xor(Lv, 1);  Lv += __shfl_xor(Lv, 2);
      Lv += __shfl_xor(Lv, 4);  Lv += __shfl_xor(Lv, 8);
      Lv += __shfl_xor(Lv, 16);
      if (l31 == 0) {
        const int row = rseti * 32 + (j & 3) + 8 * (j >> 2) + 4 * hi;
        RedA[w][row] = Lv;
      }
    }
  __syncthreads();
  if (t < QB)
    iLs[t] = 1.0f / (RedA[0][t] + RedA[1][t] + RedA[2][t] + RedA[3][t]);
  __syncthreads();

  float il[2][16];
  #pragma unroll
  for (int rseti = 0; rseti < 2; ++rseti)
    #pragma unroll
    for (int j = 0; j < 16; ++j)
      il[rseti][j] = iLs[rseti * 32 + (j & 3) + 8 * (j >> 2) + 4 * hi];

  // ---- phase B: threshold + PV ----
  v16f oA[2] = {}, oB[2] = {};
  float den[2][16] = {};

  for (int i = 0; i < 32; ++i) {
    const int c = w + 4 * i;
    v8s kb[4];
    #pragma unroll
    for (int ks = 0; ks < 4; ++ks)
      LD32(kb[ks], Kb, c * 32 + l31, ks)
    v16f sa = {}, sb = {};
    #pragma unroll
    for (int ks = 0; ks < 4; ++ks) {
      sa = __builtin_amdgcn_mfma_f32_32x32x16_bf16(qa[ks], kb[ks], sa, 0, 0, 0);
      sb = __builtin_amdgcn_mfma_f32_32x32x16_bf16(qB[ks], kb[ks], sb, 0, 0, 0);
    }
    { // stage V^T for this key column (per-wave private buffer)
      const ushort_t* vsrc = &Vh[((size_t)c * 32 + l31) * HD + hi * 32];
      #pragma unroll
      for (int qq = 0; qq < 4; ++qq) {
        uint4 vv = *(const uint4*)&vsrc[qq * 8];
        const ushort_t* pv = (const ushort_t*)&vv;
        #pragma unroll
        for (int jj = 0; jj < 8; ++jj)
          VT[w][hi * 32 + qq * 8 + jj][l31] = pv[jj];
      }
    }
    #pragma unroll
    for (int rseti = 0; rseti < 2; ++rseti) {
      #pragma unroll
      for (int j = 0; j < 16; ++j) {
        const float s = (rseti == 0) ? sa[j] : sb[j];
        const int row = (j & 3) + 8 * (j >> 2) + 4 * hi;
        float p = fexp2(s) * il[rseti][j];
        p = (p > 0.1f) ? p : 0.f;
        den[rseti][j] += p;
        Pp[w][row][l31] = f2bf(p);       // P[row][key_local]
      }
      // same-wave LDS RAW: compiler orders via lgkmcnt
      v8s pa0 = *(const v8s*)&Pp[w][l31][8 * hi];
      v8s pa1 = *(const v8s*)&Pp[w][l31][16 + 8 * hi];
      #pragma unroll
      for (int dblk = 0; dblk < 2; ++dblk) {
        v8s vb0 = *(const v8s*)&VT[w][dblk * 32 + l31][8 * hi];
        v8s vb1 = *(const v8s*)&VT[w][dblk * 32 + l31][16 + 8 * hi];
        if (rseti == 0) {
          oA[dblk] = __builtin_amdgcn_mfma_f32_32x32x16_bf16(pa0, vb0, oA[dblk], 0, 0, 0);
          oA[dblk] = __builtin_amdgcn_mfma_f32_32x32x16_bf16(pa1, vb1, oA[dblk], 0, 0, 0);
        } else {
          oB[dblk] = __builtin_amdgcn_mfma_f32_32x32x16_bf16(pa0, vb0, oB[dblk], 0, 0, 0);
          oB[dblk] = __builtin_amdgcn_mfma_f32_32x32x16_bf16(pa1, vb1, oB[dblk], 0, 0, 0);
        }
      }
    }
  }
#undef LD32

  #pragma unroll
  for (int rseti = 0; rseti < 2; ++rseti)
    #pragma unroll
    for (int j = 0; j < 16; ++j) {
      float d = den[rseti][j];
      d += __shfl_xor(d, 1); d += __shfl_xor(d, 2); d += __shfl_xor(d, 4);
      d += __shfl_xor(d, 8); d += __shfl_xor(d, 16);
      const int row = rseti * 32 + (j & 3) + 8 * (j >> 2) + 4 * hi;
      if (l31 == 0) atomicAdd(&Dsh[row], d);
    }
  #pragma unroll
  for (int rseti = 0; rseti < 2; ++rseti)
    #pragma unroll
    for (int dblk = 0; dblk < 2; ++dblk)
      #pragma unroll
      for (int j = 0; j < 16; ++j) {
        const int row = rseti * 32 + (j & 3) + 8 * (j >> 2) + 4 * hi;
        const float val = (rseti == 0) ? oA[dblk][j] : oB[dblk][j];
        atomicAdd(&Osh[row][dblk * 32 + l31], val);
      }
  __syncthreads();
  const int b = bh >> 3, h = bh & 7;
  for (int idx = t; idx < QB * HD; idx += 256) {
    const int row = idx >> 6, d = idx & 63;
    const float val = Osh[row][d] / (Dsh[row] + 1e-8f);
    Cb[((size_t)b * S_LEN + q0 + row) * HID + h * HD + d] = f2bf(val);
  }
}

// ---------------------------------------------------------------------------
// Output GEMM (bf16 in) with sparsity handling. Per-head flag bitmask:
// cold heads' ctx columns staged as ZEROS (Cb never pre-zeroed; only p2
// writes it). All-cold tile -> out = bias directly. grid (8,128) = 1024.
// ---------------------------------------------------------------------------
__global__ __launch_bounds__(256) void gemm_out(
    const ushort_t* __restrict__ X, const ushort_t* __restrict__ W,
    const float* __restrict__ bias, const int* __restrict__ Flg,
    float* __restrict__ Df)
{
  const int t = threadIdx.x;
  const int m0 = blockIdx.y * 64;
  const int e0 = blockIdx.x * 64;

  int fm = 0;   // bit h = head h flagged for this 64-row q-block
  {
    const int b = m0 >> 12, qblk = (m0 & (S_LEN - 1)) >> 6;
    #pragma unroll
    for (int h = 0; h < HEADS; ++h) {
      const int bhh = b * HEADS + h;
      const int base = (bhh >> 1) | ((bhh & 1) << 3);
      fm |= (Flg[base | (qblk << 4)] ? 1 : 0) << h;
    }
    if (!fm) {   // ctx tile is exactly zero -> out = bias
      const int row = t >> 2, c0 = (t & 3) * 16;
      #pragma unroll
      for (int g = 0; g < 4; ++g) {
        const float4 bv = *(const float4*)&bias[e0 + c0 + g * 4];
        *(float4*)&Df[(size_t)(m0 + row) * HID + e0 + c0 + g * 4] = bv;
      }
      return;
    }
  }

  __shared__ ushort_t As[64][40];
  __shared__ ushort_t Bs[64][40];
  const int lane = t & 63;
  const int l15 = lane & 15, lg = lane >> 4;
  const int w = t >> 6;
  const int wr = w >> 1, wc = w & 1;

  v4f acc[2][2] = {};
  const int srow = t >> 2, scol = (t & 3) * 8;
  const uint4 zu = {0u, 0u, 0u, 0u};

  for (int k0 = 0; k0 < HID; k0 += 32) {
    __syncthreads();
    const bool hot = (fm >> (k0 >> 6)) & 1;   // ctx cols k0..k0+31 = head k0/64
    *(uint4*)&As[srow][scol] = hot
        ? *(const uint4*)&X[(size_t)(m0 + srow) * HID + k0 + scol]
        : zu;
    *(uint4*)&Bs[srow][scol] =
        *(const uint4*)&W[(size_t)(e0 + srow) * HID + k0 + scol];
    __syncthreads();
    v8s a[2], b[2];
    #pragma unroll
    for (int fr = 0; fr < 2; ++fr)
      a[fr] = *(const v8s*)&As[wr * 32 + 16 * fr + l15][8 * lg];
    #pragma unroll
    for (int fc = 0; fc < 2; ++fc)
      b[fc] = *(const v8s*)&Bs[wc * 32 + 16 * fc + l15][8 * lg];
    #pragma unroll
    for (int fr = 0; fr < 2; ++fr)
      #pragma unroll
      for (int fc = 0; fc < 2; ++fc)
        acc[fr][fc] = __builtin_amdgcn_mfma_f32_16x16x32_bf16(a[fr], b[fc], acc[fr][fc], 0, 0, 0);
  }

  #pragma unroll
  for (int fr = 0; fr < 2; ++fr)
    #pragma unroll
    for (int fc = 0; fc < 2; ++fc) {
      const int e = e0 + wc * 32 + 16 * fc + l15;
      const float bval = bias[e];
      #pragma unroll
      for (int r = 0; r < 4; ++r) {
        const int m = m0 + wr * 32 + 16 * fr + 4 * lg + r;
        Df[(size_t)m * HID + e] = acc[fr][fc][r] + bval;
      }
    }
}

// ---------------------------------------------------------------------------
extern "C" void kernel_launch(void* const* d_in, const int* in_sizes, int n_in,
                              void* d_out, int out_size, void* d_ws, size_t ws_size,
                              hipStream_t stream) {
  const float* x  = (const float*)d_in[0];
  const float* Wq = (const float*)d_in[1];
  const float* bq = (const float*)d_in[2];
  const float* Wk = (const float*)d_in[3];
  const float* bk = (const float*)d_in[4];
  const float* Wv = (const float*)d_in[5];
  const float* bv = (const float*)d_in[6];
  const float* Wo = (const float*)d_in[7];
  const float* bo = (const float*)d_in[8];

  int*      Flg  = (int*)d_ws;                  // [1024]
  ushort_t* xb   = (ushort_t*)(Flg + NBLK);     // bf16 x
  ushort_t* wqb  = xb + NX;                     // 3 QKV weights contiguous
  ushort_t* wob  = wqb + 3 * WSZ;
  ushort_t* Qf   = wob + WSZ;                   // frag-linear-16
  ushort_t* Kf   = Qf + NX;                     // frag-linear-16
  ushort_t* Vw   = Kf + NX;                     // plain [B,H,S,HD]
  ushort_t* Cb   = Vw + NX;                     // ctx bf16 (p2-written only)

  const float qscale = 0.125f * 1.44269504f;    // softmax scale * log2(e)

  cvt_k<<<(NX + 4 * WSZ) / 1024, 256, 0, stream>>>(x, Wq, Wk, Wv, Wo, xb);

  gemm_qkv<<<dim3(12, 64), 256, 0, stream>>>(
      xb, wqb, bq, bk, bv, Qf, Kf, Vw, qscale);

  attn_p1<<<NBLK, 512, 0, stream>>>(Qf, Kf, Flg);
  attn_p2<<<NBLK, 256, 0, stream>>>(Qf, Kf, Vw, Cb, Flg);

  gemm_out<<<dim3(8, 128), 256, 0, stream>>>(Cb, wob, bo, Flg, (float*)d_out);
}